// Round 1
// baseline (47.267 us; speedup 1.0000x reference)
//
#include <hip/hip_runtime.h>

typedef unsigned short u16;
typedef __attribute__((ext_vector_type(8))) short bf16x8;
typedef __attribute__((ext_vector_type(4))) float f32x4;

#define CIN 128
#define OC 128
#define NP 1024      // 32*32 spatial
#define KTOT 1152    // 9*128, k = rs*128 + c
#define NSTEP 18
#define BK 64

__device__ __forceinline__ u16 f2bf(float f) {
  unsigned b = __builtin_bit_cast(unsigned, f);
  b += 0x7fffu + ((b >> 16) & 1u);   // RNE; inputs are finite
  return (u16)(b >> 16);
}

// w[i][oc][c][r][s] f32  ->  wbf[i][oc][rs][c] bf16   (k = rs*128 + c)
__global__ void wcvt_kernel(const float* __restrict__ w, u16* __restrict__ wbf) {
  __shared__ u16 lds[KTOT];
  const int blk = blockIdx.x;        // i*128 + oc
  const int t = threadIdx.x;         // 0..127
  const float* src = w + (size_t)blk * KTOT;
  u16* dst = wbf + (size_t)blk * KTOT;
#pragma unroll
  for (int e = 0; e < 9; ++e) {
    int idx = t + 128 * e;           // coalesced read
    lds[idx] = f2bf(src[idx]);       // lds[c*9+rs] layout (input order)
  }
  __syncthreads();
#pragma unroll
  for (int e = 0; e < 9; ++e) {
    int o = t + 128 * e;             // o = rs*128 + c ; rs=e, c=t
    dst[o] = lds[t * 9 + e];         // coalesced write
  }
}

__global__ __launch_bounds__(256, 2) void conv_mfma(
    const float* __restrict__ x,     // [32][128][32][32]
    const u16* __restrict__ wbf,     // [32][128][1152]
    const float* __restrict__ bias,  // [32][1][128]
    float* __restrict__ out) {       // [32][1][128][32][32]
  __shared__ u16 Asw[OC * BK];       // 16 KB, XOR-swizzled rows of 128B
  __shared__ u16 Bsw[64 * BK];       // 8 KB

  const int i  = blockIdx.y;
  const int pt = blockIdx.x;         // 16 spatial tiles of 64
  const int p0 = pt * 64;
  const int tid = (int)threadIdx.x;
  const int lane = tid & 63;
  const int wid = tid >> 6;
  const int wm = wid >> 1;           // wave tile: 64 oc x 32 p
  const int wn = wid & 1;

  const float* xi = x + (size_t)i * CIN * NP;
  const u16*   wi = wbf + (size_t)i * OC * KTOT;

  // B gather mapping: thread -> (p_local, c-chunk of 16)
  const int pl = tid >> 2;           // 0..63
  const int kc = tid & 3;            // 0..3
  const int y  = (p0 + pl) >> 5;
  const int xc = pl & 31;

  // A staging mapping: thread -> (oc row, k-half of 32)
  const int arow = tid >> 1;         // 0..127
  const int kh = tid & 1;
  const u16* asrc0 = wi + arow * KTOT + kh * 32;

  f32x4 acc[4][2];
#pragma unroll
  for (int mi = 0; mi < 4; ++mi)
#pragma unroll
    for (int ni = 0; ni < 2; ++ni)
      acc[mi][ni] = (f32x4){0.f, 0.f, 0.f, 0.f};

  for (int step = 0; step < NSTEP; ++step) {
    const int k0 = step * BK;
    const int rs = step >> 1;          // uniform (r,s) per K-step
    const int r  = rs / 3;
    const int dy = r - 1;
    const int dx = (rs - r * 3) - 1;
    const int c0 = (step & 1) * 64;

    __syncthreads();   // previous step's LDS reads done

    // ---- stage A: wbf rows, 16B vector loads, swizzled ds_write ----
    {
      const u16* a = asrc0 + k0;
      bf16x8 av[4];
#pragma unroll
      for (int e = 0; e < 4; ++e)
        av[e] = *(const bf16x8*)(a + e * 8);
#pragma unroll
      for (int e = 0; e < 4; ++e) {
        int slot = (kh * 4 + e) ^ (arow & 7);
        *(bf16x8*)(&Asw[arow * BK + slot * 8]) = av[e];
      }
    }

    // ---- stage B: im2col gather (uniform shift per step) ----
    {
      const int iy = y + dy;
      const int ix = xc + dx;
      const bool valid = ((unsigned)iy < 32u) & ((unsigned)ix < 32u);
      float v[16];
      if (valid) {
        const float* bsrc = xi + (c0 + kc * 16) * NP + iy * 32 + ix;
#pragma unroll
        for (int j = 0; j < 16; ++j) v[j] = bsrc[j * NP];
      } else {
#pragma unroll
        for (int j = 0; j < 16; ++j) v[j] = 0.f;
      }
      bf16x8 lo, hi;
#pragma unroll
      for (int j = 0; j < 8; ++j) {
        lo[j] = (short)f2bf(v[j]);
        hi[j] = (short)f2bf(v[j + 8]);
      }
      const int s0 = 2 * kc;
      *(bf16x8*)(&Bsw[pl * BK + ((s0    ) ^ (pl & 7)) * 8]) = lo;
      *(bf16x8*)(&Bsw[pl * BK + ((s0 + 1) ^ (pl & 7)) * 8]) = hi;
    }

    __syncthreads();   // staging visible

    // ---- math: 16 MFMAs per wave per K-step ----
#pragma unroll
    for (int kkk = 0; kkk < 2; ++kkk) {
      bf16x8 af[4], bfr[2];
#pragma unroll
      for (int mi = 0; mi < 4; ++mi) {
        int row = wm * 64 + mi * 16 + (lane & 15);
        int slot = (kkk * 4 + (lane >> 4)) ^ (row & 7);
        af[mi] = *(const bf16x8*)(&Asw[row * BK + slot * 8]);
      }
#pragma unroll
      for (int ni = 0; ni < 2; ++ni) {
        int prow = wn * 32 + ni * 16 + (lane & 15);
        int slot = (kkk * 4 + (lane >> 4)) ^ (prow & 7);
        bfr[ni] = *(const bf16x8*)(&Bsw[prow * BK + slot * 8]);
      }
#pragma unroll
      for (int mi = 0; mi < 4; ++mi)
#pragma unroll
        for (int ni = 0; ni < 2; ++ni)
          acc[mi][ni] = __builtin_amdgcn_mfma_f32_16x16x32_bf16(
              af[mi], bfr[ni], acc[mi][ni], 0, 0, 0);
    }
  }

  // ---- epilogue: C/D layout col=lane&15, row=(lane>>4)*4+j ----
  const int row0 = (lane >> 4) * 4;
  const int coln = lane & 15;
#pragma unroll
  for (int mi = 0; mi < 4; ++mi) {
    int oc = wm * 64 + mi * 16 + row0;
#pragma unroll
    for (int jj = 0; jj < 4; ++jj) {
      float bv = bias[i * OC + oc + jj];
      float* orow = out + ((size_t)i * OC + oc + jj) * NP;
#pragma unroll
      for (int ni = 0; ni < 2; ++ni) {
        int pg = p0 + wn * 32 + ni * 16 + coln;
        orow[pg] = acc[mi][ni][jj] + bv;
      }
    }
  }
}

extern "C" void kernel_launch(void* const* d_in, const int* in_sizes, int n_in,
                              void* d_out, int out_size, void* d_ws, size_t ws_size,
                              hipStream_t stream) {
  const float* x    = (const float*)d_in[0];
  const float* w    = (const float*)d_in[1];
  const float* bias = (const float*)d_in[2];
  float* out = (float*)d_out;
  u16* wbf = (u16*)d_ws;   // needs 32*128*1152*2 = 9.44 MB

  wcvt_kernel<<<dim3(32 * OC), dim3(128), 0, stream>>>(w, wbf);
  conv_mfma<<<dim3(16, 32), dim3(256), 0, stream>>>(x, wbf, bias, out);
}

// Round 4
// 40.179 us; speedup vs baseline: 1.1764x; 1.1764x over previous
//
#include <hip/hip_runtime.h>

typedef unsigned short u16;
typedef unsigned int u32;
typedef __attribute__((ext_vector_type(8))) short bf16x8;
typedef __attribute__((ext_vector_type(4))) unsigned int u32x4;
typedef __attribute__((ext_vector_type(4))) float f32x4;

#define CIN 128
#define OC 128
#define NP 1024      // 32*32 spatial
#define KTOT 1152    // 9*128, k = rs*128 + c
#define NSTEP 18
#define BK 64

__device__ __forceinline__ u16 f2bf(float f) {
  unsigned b = __builtin_bit_cast(unsigned, f);
  b += 0x7fffu + ((b >> 16) & 1u);   // RNE; inputs are finite
  return (u16)(b >> 16);
}

// packs cvt_bf16(lo) into [15:0], cvt_bf16(hi) into [31:16] (RNE)
__device__ __forceinline__ u32 cvtpk(float lo, float hi) {
  u32 r;
  asm("v_cvt_pk_bf16_f32 %0, %1, %2" : "=v"(r) : "v"(lo), "v"(hi));
  return r;
}

// w[i][oc][c][r][s] f32  ->  wbf[i][oc][rs][c] bf16   (k = rs*128 + c)
__global__ void wcvt_kernel(const float* __restrict__ w, u16* __restrict__ wbf) {
  __shared__ u16 lds[KTOT];
  const int blk = blockIdx.x;        // i*128 + oc
  const int t = threadIdx.x;         // 0..127
  const float* src = w + (size_t)blk * KTOT;
  u16* dst = wbf + (size_t)blk * KTOT;
#pragma unroll
  for (int e = 0; e < 9; ++e) {
    int idx = t + 128 * e;           // coalesced read
    lds[idx] = f2bf(src[idx]);       // lds[c*9+rs] layout (input order)
  }
  __syncthreads();
#pragma unroll
  for (int e = 0; e < 9; ++e) {
    int o = t + 128 * e;             // o = rs*128 + c ; rs=e, c=t
    dst[o] = lds[t * 9 + e];         // coalesced write
  }
}

__global__ __launch_bounds__(256, 2) void conv_mfma(
    const float* __restrict__ x,     // [32][128][32][32] f32
    const u16* __restrict__ wbf,     // [32][128][1152] bf16
    const float* __restrict__ bias,  // [32][1][128]
    float* __restrict__ out) {       // [32][1][128][32][32]
  __shared__ u16 Asw[2][OC * BK];    // 2 x 16 KB, XOR-swizzled 128B rows
  __shared__ u16 Bsw[2][64 * BK];    // 2 x 8 KB

  // flat grid 512 = 8 XCDs x 64; bijective XCD swizzle -> 4 samples per XCD
  const int wg = (int)blockIdx.x;
  const int swz = (wg & 7) * 64 + (wg >> 3);
  const int i  = swz >> 4;
  const int pt = swz & 15;
  const int p0 = pt * 64;
  const int tid = (int)threadIdx.x;
  const int lane = tid & 63;
  const int wid = tid >> 6;
  const int wm = wid >> 1;           // wave tile: 64 oc x 32 p
  const int wn = wid & 1;

  const float* xi = x + (size_t)i * CIN * NP;
  const u16*   wi = wbf + (size_t)i * OC * KTOT;

  // B gather mapping (round-1 proven): thread -> (p_local, 16-channel chunk)
  const int pl = tid >> 2;           // 0..63
  const int kc = tid & 3;            // 0..3
  const int y  = (p0 + pl) >> 5;
  const int xc = pl & 31;

  // A staging mapping: thread -> (oc row, k-half of 32)
  const int arow = tid >> 1;         // 0..127
  const int kh = tid & 1;
  const u16* abase = wi + arow * KTOT + kh * 32;

  f32x4 acc[4][2];
#pragma unroll
  for (int mi = 0; mi < 4; ++mi)
#pragma unroll
    for (int ni = 0; ni < 2; ++ni)
      acc[mi][ni] = (f32x4){0.f, 0.f, 0.f, 0.f};

  bf16x8 ar[4];
  float v[16];

#define LOADA(step) do {                                        \
    const u16* _a = abase + (step) * BK;                        \
    _Pragma("unroll")                                           \
    for (int e = 0; e < 4; ++e) ar[e] = *(const bf16x8*)(_a + e * 8); \
  } while (0)

  // issue the 16 strided f32 loads (bounds-checked, zero halo)
#define LOADB(step) do {                                        \
    const int _rs = (step) >> 1;                                \
    const int _r  = _rs / 3;                                    \
    const int _dy = _r - 1, _dx = (_rs - _r * 3) - 1;           \
    const int _c0 = ((step) & 1) * 64;                          \
    const int _iy = y + _dy, _ix = xc + _dx;                    \
    const bool _valid = ((unsigned)_iy < 32u) & ((unsigned)_ix < 32u); \
    if (_valid) {                                               \
      const float* _b = xi + (size_t)(_c0 + kc * 16) * NP + _iy * 32 + _ix; \
      _Pragma("unroll")                                         \
      for (int j = 0; j < 16; ++j) v[j] = _b[j * NP];           \
    } else {                                                    \
      _Pragma("unroll")                                         \
      for (int j = 0; j < 16; ++j) v[j] = 0.f;                  \
    }                                                           \
  } while (0)

#define STOREA(buf) do {                                        \
    _Pragma("unroll")                                           \
    for (int e = 0; e < 4; ++e) {                               \
      int _slot = (kh * 4 + e) ^ (arow & 7);                    \
      *(bf16x8*)(&Asw[buf][arow * BK + _slot * 8]) = ar[e];     \
    }                                                           \
  } while (0)

  // pack v[16] -> 2x 16B and write to swizzled slots (write-late; the
  // vmcnt wait on v[] lands here, after the MFMA phase)
#define PACK_STOREB(buf) do {                                   \
    u32x4 _b0, _b1;                                             \
    _Pragma("unroll")                                           \
    for (int jj = 0; jj < 4; ++jj) {                            \
      _b0[jj] = cvtpk(v[2 * jj],     v[2 * jj + 1]);            \
      _b1[jj] = cvtpk(v[2 * jj + 8], v[2 * jj + 9]);            \
    }                                                           \
    const int _s0 = kc * 2;                                     \
    *(u32x4*)(&Bsw[buf][pl * BK + ((_s0    ) ^ (pl & 7)) * 8]) = _b0; \
    *(u32x4*)(&Bsw[buf][pl * BK + ((_s0 + 1) ^ (pl & 7)) * 8]) = _b1; \
  } while (0)

  LOADA(0); LOADB(0);
  STOREA(0); PACK_STOREB(0);
  __syncthreads();

#pragma unroll
  for (int step = 0; step < NSTEP; ++step) {
    const int cur = step & 1;

    // issue next step's global loads early; latency hides under MFMA phase
    if (step + 1 < NSTEP) { LOADA(step + 1); LOADB(step + 1); }

    // ---- math: 16 MFMAs per wave per K-step ----
#pragma unroll
    for (int kkk = 0; kkk < 2; ++kkk) {
      bf16x8 af[4], bfr[2];
#pragma unroll
      for (int mi = 0; mi < 4; ++mi) {
        int row = wm * 64 + mi * 16 + (lane & 15);
        int slot = (kkk * 4 + (lane >> 4)) ^ (row & 7);
        af[mi] = *(const bf16x8*)(&Asw[cur][row * BK + slot * 8]);
      }
#pragma unroll
      for (int ni = 0; ni < 2; ++ni) {
        int prow = wn * 32 + ni * 16 + (lane & 15);
        int slot = (kkk * 4 + (lane >> 4)) ^ (prow & 7);
        bfr[ni] = *(const bf16x8*)(&Bsw[cur][prow * BK + slot * 8]);
      }
#pragma unroll
      for (int mi = 0; mi < 4; ++mi)
#pragma unroll
        for (int ni = 0; ni < 2; ++ni)
          acc[mi][ni] = __builtin_amdgcn_mfma_f32_16x16x32_bf16(
              af[mi], bfr[ni], acc[mi][ni], 0, 0, 0);
    }

    // write next tile into the other buffer (one barrier per step;
    // write-after-read on buf[cur^1] is protected by the previous barrier)
    if (step + 1 < NSTEP) { STOREA(cur ^ 1); PACK_STOREB(cur ^ 1); }
    __syncthreads();
  }

  // ---- epilogue: C/D layout col=lane&15, row=(lane>>4)*4+j ----
  const int row0 = (lane >> 4) * 4;
  const int coln = lane & 15;
#pragma unroll
  for (int mi = 0; mi < 4; ++mi) {
    int oc = wm * 64 + mi * 16 + row0;
#pragma unroll
    for (int jj = 0; jj < 4; ++jj) {
      float bv = bias[i * OC + oc + jj];
      float* orow = out + ((size_t)i * OC + oc + jj) * NP;
#pragma unroll
      for (int ni = 0; ni < 2; ++ni) {
        int pg = p0 + wn * 32 + ni * 16 + coln;
        orow[pg] = acc[mi][ni][jj] + bv;
      }
    }
  }
#undef LOADA
#undef LOADB
#undef STOREA
#undef PACK_STOREB
}

extern "C" void kernel_launch(void* const* d_in, const int* in_sizes, int n_in,
                              void* d_out, int out_size, void* d_ws, size_t ws_size,
                              hipStream_t stream) {
  const float* x    = (const float*)d_in[0];
  const float* w    = (const float*)d_in[1];
  const float* bias = (const float*)d_in[2];
  float* out = (float*)d_out;
  u16* wbf = (u16*)d_ws;   // 32*128*1152 u16 = 9.44 MB

  wcvt_kernel<<<dim3(32 * OC), dim3(128), 0, stream>>>(w, wbf);
  conv_mfma<<<dim3(512), dim3(256), 0, stream>>>(x, wbf, bias, out);
}

// Round 5
// 33.177 us; speedup vs baseline: 1.4247x; 1.2111x over previous
//
#include <hip/hip_runtime.h>

typedef unsigned short u16;
typedef unsigned int u32;
typedef __attribute__((ext_vector_type(2))) unsigned int u32x2;
typedef __attribute__((ext_vector_type(8))) short bf16x8;
typedef __attribute__((ext_vector_type(4))) float f32x4;

#define CIN 128
#define OC 128
#define NP 1024      // 32*32 spatial
#define KTOT 1152    // 9*128, k = rs*128 + c
#define NSTEP 18
#define BK 64

__device__ __forceinline__ u16 f2bf(float f) {
  unsigned b = __builtin_bit_cast(unsigned, f);
  b += 0x7fffu + ((b >> 16) & 1u);   // RNE; inputs are finite
  return (u16)(b >> 16);
}

// w[i][oc][c][r][s] f32  ->  wbf[i][oc][rs][c] bf16   (k = rs*128 + c)
__global__ void wcvt_kernel(const float* __restrict__ w, u16* __restrict__ wbf) {
  __shared__ u16 lds[KTOT];
  const int blk = blockIdx.x;        // i*128 + oc
  const int t = threadIdx.x;         // 0..127
  const float* src = w + (size_t)blk * KTOT;
  u16* dst = wbf + (size_t)blk * KTOT;
#pragma unroll
  for (int e = 0; e < 9; ++e) {
    int idx = t + 128 * e;           // coalesced read
    lds[idx] = f2bf(src[idx]);       // lds[c*9+rs] layout (input order)
  }
  __syncthreads();
#pragma unroll
  for (int e = 0; e < 9; ++e) {
    int o = t + 128 * e;             // o = rs*128 + c ; rs=e, c=t
    dst[o] = lds[t * 9 + e];         // coalesced write
  }
}

// Xs: 4 rows x 34 cols x 128 ch bf16, stored as 16B slots with XOR swizzle:
//   slot'(cslot, col) = cslot ^ (col & 7);  u16 index = ((r*34+col)*16 + slot')*8 + (c&7)
__global__ __launch_bounds__(256, 2) void conv_mfma(
    const float* __restrict__ x,     // [32][128][32][32] f32
    const u16* __restrict__ wbf,     // [32][128][1152] bf16
    const float* __restrict__ bias,  // [32][1][128]
    float* __restrict__ out) {       // [32][1][128][32][32]
  __shared__ u16 Xs[4 * 34 * 128];   // 34,816 B x-stage (read-only during K-loop)
  __shared__ u16 Asw[2][OC * BK];    // 2 x 16 KB, XOR-swizzled 128B rows

  // flat grid 512 = 8 XCDs x 64; bijective XCD swizzle -> 4 samples per XCD
  const int wg = (int)blockIdx.x;
  const int swz = (wg & 7) * 64 + (wg >> 3);
  const int i  = swz >> 4;
  const int pt = swz & 15;
  const int p0 = pt * 64;           // 64 pixels = image rows {2pt, 2pt+1}
  const int tid = (int)threadIdx.x;
  const int lane = tid & 63;
  const int wid = tid >> 6;
  const int wm = wid >> 1;           // wave tile: 64 oc x 32 p
  const int wn = wid & 1;

  const float* xi = x + (size_t)i * CIN * NP;
  const u16*   wi = wbf + (size_t)i * OC * KTOT;

  // A staging mapping (r4-proven): thread -> (oc row, k-half of 32)
  const int arow = tid >> 1;         // 0..127
  const int kh = tid & 1;
  const u16* abase = wi + arow * KTOT + kh * 32;

  bf16x8 ar[4];

#define LOADA(step) do {                                        \
    const u16* _a = abase + (step) * BK;                        \
    _Pragma("unroll")                                           \
    for (int e = 0; e < 4; ++e) ar[e] = *(const bf16x8*)(_a + e * 8); \
  } while (0)

#define STOREA(buf) do {                                        \
    _Pragma("unroll")                                           \
    for (int e = 0; e < 4; ++e) {                               \
      int _slot = (kh * 4 + e) ^ (arow & 7);                    \
      *(bf16x8*)(&Asw[buf][arow * BK + _slot * 8]) = ar[e];     \
    }                                                           \
  } while (0)

  // ---------- one-time x-stage: rows yr = 2pt-1 .. 2pt+2 ----------
  {
    const int xx = tid & 31;         // image col 0..31 -> LDS col xx+1
    const int cg = tid >> 5;         // channel group 0..7 (16 ch each)
    const int col = xx + 1;
    const int csw = col & 7;
#pragma unroll
    for (int r = 0; r < 4; ++r) {
      const int yr = 2 * pt - 1 + r;
      float v[16];
      if ((unsigned)yr < 32u) {
        const float* src = xi + (size_t)(cg * 16) * NP + yr * 32 + xx;
#pragma unroll
        for (int j = 0; j < 16; ++j) v[j] = src[(size_t)j * NP];
      } else {
#pragma unroll
        for (int j = 0; j < 16; ++j) v[j] = 0.f;
      }
      u32 pk[8];
#pragma unroll
      for (int m = 0; m < 8; ++m)
        pk[m] = (u32)f2bf(v[2 * m]) | ((u32)f2bf(v[2 * m + 1]) << 16);
      // 4x 8B writes: q covers channels cg*16 + 4q .. +3
#pragma unroll
      for (int q = 0; q < 4; ++q) {
        const int cslot = cg * 2 + (q >> 1);
        const int idx = ((r * 34 + col) * 16 + (cslot ^ csw)) * 8 + (q & 1) * 4;
        *(u32x2*)(&Xs[idx]) = (u32x2){pk[2 * q], pk[2 * q + 1]};
      }
    }
    // column halo (col 0 and 33): zeros, 4 rows x 2 cols x 16 slots
    if (tid < 128) {
      const int r = tid >> 5;
      const int hc = ((tid >> 4) & 1) ? 33 : 0;
      const int s = tid & 15;
      const int idx = ((r * 34 + hc) * 16 + (s ^ (hc & 7))) * 8;
      *(bf16x8*)(&Xs[idx]) = (bf16x8){0, 0, 0, 0, 0, 0, 0, 0};
    }
  }

  f32x4 acc[4][2];
#pragma unroll
  for (int mi = 0; mi < 4; ++mi)
#pragma unroll
    for (int ni = 0; ni < 2; ++ni)
      acc[mi][ni] = (f32x4){0.f, 0.f, 0.f, 0.f};

  // per-lane B-read constants: pixel p_local = wn*32 + ni*16 + (lane&15)
  // image col = ni*16 + (lane&15)  (wn selects the image row)
  const int cb0 = (lane & 15) + 1;         // ni=0 LDS col before dx
  const int lhi = lane >> 4;               // k-subslot 0..3

  LOADA(0);
  STOREA(0);
  __syncthreads();

#pragma unroll
  for (int step = 0; step < NSTEP; ++step) {
    const int cur = step & 1;
    const int rs = step >> 1;
    const int r3 = rs / 3;
    const int dy = r3 - 1;
    const int dx = (rs - r3 * 3) - 1;
    const int c0s = (step & 1) * 8;        // channel-slot base (64ch/8)
    const int rw = (wn + 1 + dy) * 34;     // x-stage row base (in cols)

    // prefetch next A-tile (latency hides under MFMA phase)
    if (step + 1 < NSTEP) LOADA(step + 1);

    // ---- math: 16 MFMAs per wave per K-step ----
#pragma unroll
    for (int kkk = 0; kkk < 2; ++kkk) {
      bf16x8 af[4], bfr[2];
#pragma unroll
      for (int mi = 0; mi < 4; ++mi) {
        int row = wm * 64 + mi * 16 + (lane & 15);
        int slot = (kkk * 4 + lhi) ^ (row & 7);
        af[mi] = *(const bf16x8*)(&Asw[cur][row * BK + slot * 8]);
      }
#pragma unroll
      for (int ni = 0; ni < 2; ++ni) {
        const int col = cb0 + ni * 16 + dx;
        const int cslot = c0s + kkk * 4 + lhi;
        const int idx = ((rw + col) * 16 + (cslot ^ (col & 7))) * 8;
        bfr[ni] = *(const bf16x8*)(&Xs[idx]);
      }
#pragma unroll
      for (int mi = 0; mi < 4; ++mi)
#pragma unroll
        for (int ni = 0; ni < 2; ++ni)
          acc[mi][ni] = __builtin_amdgcn_mfma_f32_16x16x32_bf16(
              af[mi], bfr[ni], acc[mi][ni], 0, 0, 0);
    }

    // stage next A into the other buffer (WAR protected by previous barrier)
    if (step + 1 < NSTEP) STOREA(cur ^ 1);
    __syncthreads();
  }

  // ---- epilogue (r4-proven): C/D col=lane&15, row=(lane>>4)*4+j ----
  const int row0 = (lane >> 4) * 4;
  const int coln = lane & 15;
#pragma unroll
  for (int mi = 0; mi < 4; ++mi) {
    int oc = wm * 64 + mi * 16 + row0;
#pragma unroll
    for (int jj = 0; jj < 4; ++jj) {
      float bv = bias[i * OC + oc + jj];
      float* orow = out + ((size_t)i * OC + oc + jj) * NP;
#pragma unroll
      for (int ni = 0; ni < 2; ++ni) {
        int pg = p0 + wn * 32 + ni * 16 + coln;
        orow[pg] = acc[mi][ni][jj] + bv;
      }
    }
  }
#undef LOADA
#undef STOREA
}

extern "C" void kernel_launch(void* const* d_in, const int* in_sizes, int n_in,
                              void* d_out, int out_size, void* d_ws, size_t ws_size,
                              hipStream_t stream) {
  const float* x    = (const float*)d_in[0];
  const float* w    = (const float*)d_in[1];
  const float* bias = (const float*)d_in[2];
  float* out = (float*)d_out;
  u16* wbf = (u16*)d_ws;   // 32*128*1152 u16 = 9.44 MB

  wcvt_kernel<<<dim3(32 * OC), dim3(128), 0, stream>>>(w, wbf);
  conv_mfma<<<dim3(512), dim3(256), 0, stream>>>(x, wbf, bias, out);
}

// Round 6
// 30.362 us; speedup vs baseline: 1.5568x; 1.0927x over previous
//
#include <hip/hip_runtime.h>

typedef unsigned short u16;
typedef unsigned int u32;
typedef __attribute__((ext_vector_type(2))) unsigned int u32x2;
typedef __attribute__((ext_vector_type(8))) short bf16x8;
typedef __attribute__((ext_vector_type(4))) float f32x4;

#define CIN 128
#define OC 128
#define NP 1024      // 32*32 spatial
#define KTOT 1152    // 9*128, k = rs*128 + c
#define NSTEP 18
#define BK 64

__device__ __forceinline__ u16 f2bf(float f) {
  unsigned b = __builtin_bit_cast(unsigned, f);
  b += 0x7fffu + ((b >> 16) & 1u);   // RNE; inputs are finite
  return (u16)(b >> 16);
}

// w[i][oc][c][r][s] f32  ->  wbf[i][oc][rs][c] bf16   (k = rs*128 + c)
__global__ void wcvt_kernel(const float* __restrict__ w, u16* __restrict__ wbf) {
  __shared__ u16 lds[KTOT];
  const int blk = blockIdx.x;        // i*128 + oc
  const int t = threadIdx.x;         // 0..127
  const float* src = w + (size_t)blk * KTOT;
  u16* dst = wbf + (size_t)blk * KTOT;
#pragma unroll
  for (int e = 0; e < 9; ++e) {
    int idx = t + 128 * e;           // coalesced read
    lds[idx] = f2bf(src[idx]);       // lds[c*9+rs] layout (input order)
  }
  __syncthreads();
#pragma unroll
  for (int e = 0; e < 9; ++e) {
    int o = t + 128 * e;             // o = rs*128 + c ; rs=e, c=t
    dst[o] = lds[t * 9 + e];         // coalesced write
  }
}

// Xs: 4 rows x 34 cols x 128 ch bf16, stored as 16B slots with XOR swizzle:
//   slot'(cslot, col) = cslot ^ (col & 7);  u16 index = ((r*34+col)*16 + slot')*8 + (c&7)
// LDS total = 34,816 (Xs) + 16,384 (Asw) = 50 KB -> 3 blocks/CU, 12 waves/CU.
__global__ __launch_bounds__(256, 3) void conv_mfma(
    const float* __restrict__ x,     // [32][128][32][32] f32
    const u16* __restrict__ wbf,     // [32][128][1152] bf16
    const float* __restrict__ bias,  // [32][1][128]
    float* __restrict__ out) {       // [32][1][128][32][32]
  __shared__ u16 Xs[4 * 34 * 128];   // x-stage, read-only during K-loop
  __shared__ u16 Asw[OC * BK];       // single-buffered A tile, XOR-swizzled

  // flat grid 512 = 8 XCDs x 64; bijective XCD swizzle -> 4 samples per XCD
  const int wg = (int)blockIdx.x;
  const int swz = (wg & 7) * 64 + (wg >> 3);
  const int i  = swz >> 4;
  const int pt = swz & 15;
  const int p0 = pt * 64;           // 64 pixels = image rows {2pt, 2pt+1}
  const int tid = (int)threadIdx.x;
  const int lane = tid & 63;
  const int wid = tid >> 6;
  const int wm = wid >> 1;           // wave tile: 64 oc x 32 p
  const int wn = wid & 1;

  const float* xi = x + (size_t)i * CIN * NP;
  const u16*   wi = wbf + (size_t)i * OC * KTOT;

  // A staging mapping (proven): thread -> (oc row, k-half of 32)
  const int arow = tid >> 1;         // 0..127
  const int kh = tid & 1;
  const u16* abase = wi + arow * KTOT + kh * 32;

  bf16x8 ar[4];

#define LOADA(step) do {                                        \
    const u16* _a = abase + (step) * BK;                        \
    _Pragma("unroll")                                           \
    for (int e = 0; e < 4; ++e) ar[e] = *(const bf16x8*)(_a + e * 8); \
  } while (0)

#define STOREA() do {                                           \
    _Pragma("unroll")                                           \
    for (int e = 0; e < 4; ++e) {                               \
      int _slot = (kh * 4 + e) ^ (arow & 7);                    \
      *(bf16x8*)(&Asw[arow * BK + _slot * 8]) = ar[e];          \
    }                                                           \
  } while (0)

  // ---------- one-time x-stage: rows yr = 2pt-1 .. 2pt+2 ----------
  {
    const int xx = tid & 31;         // image col 0..31 -> LDS col xx+1
    const int cg = tid >> 5;         // channel group 0..7 (16 ch each)
    const int col = xx + 1;
    const int csw = col & 7;
#pragma unroll
    for (int r = 0; r < 4; ++r) {
      const int yr = 2 * pt - 1 + r;
      float v[16];
      if ((unsigned)yr < 32u) {
        const float* src = xi + (size_t)(cg * 16) * NP + yr * 32 + xx;
#pragma unroll
        for (int j = 0; j < 16; ++j) v[j] = src[(size_t)j * NP];
      } else {
#pragma unroll
        for (int j = 0; j < 16; ++j) v[j] = 0.f;
      }
      u32 pk[8];
#pragma unroll
      for (int m = 0; m < 8; ++m)
        pk[m] = (u32)f2bf(v[2 * m]) | ((u32)f2bf(v[2 * m + 1]) << 16);
      // 4x 8B writes: q covers channels cg*16 + 4q .. +3
#pragma unroll
      for (int q = 0; q < 4; ++q) {
        const int cslot = cg * 2 + (q >> 1);
        const int idx = ((r * 34 + col) * 16 + (cslot ^ csw)) * 8 + (q & 1) * 4;
        *(u32x2*)(&Xs[idx]) = (u32x2){pk[2 * q], pk[2 * q + 1]};
      }
    }
    // column halo (col 0 and 33): zeros, 4 rows x 2 cols x 16 slots
    if (tid < 128) {
      const int r = tid >> 5;
      const int hc = ((tid >> 4) & 1) ? 33 : 0;
      const int s = tid & 15;
      const int idx = ((r * 34 + hc) * 16 + (s ^ (hc & 7))) * 8;
      *(bf16x8*)(&Xs[idx]) = (bf16x8){0, 0, 0, 0, 0, 0, 0, 0};
    }
  }

  f32x4 acc[4][2];
#pragma unroll
  for (int mi = 0; mi < 4; ++mi)
#pragma unroll
    for (int ni = 0; ni < 2; ++ni)
      acc[mi][ni] = (f32x4){0.f, 0.f, 0.f, 0.f};

  // per-lane B-read constants: pixel p_local = wn*32 + ni*16 + (lane&15)
  const int cb0 = (lane & 15) + 1;         // ni=0 LDS col before dx
  const int lhi = lane >> 4;               // k-subslot 0..3

  LOADA(0);
  STOREA();
  __syncthreads();

#pragma unroll
  for (int step = 0; step < NSTEP; ++step) {
    const int rs = step >> 1;
    const int r3 = rs / 3;
    const int dy = r3 - 1;
    const int dx = (rs - r3 * 3) - 1;
    const int c0s = (step & 1) * 8;        // channel-slot base (64ch/8)
    const int rw = (wn + 1 + dy) * 34;     // x-stage row base (in cols)

    // prefetch next A-tile into registers; stays in flight across barriers
    if (step + 1 < NSTEP) LOADA(step + 1);

    // ---- math: 16 MFMAs per wave per K-step ----
    __builtin_amdgcn_s_setprio(1);
#pragma unroll
    for (int kkk = 0; kkk < 2; ++kkk) {
      bf16x8 af[4], bfr[2];
#pragma unroll
      for (int mi = 0; mi < 4; ++mi) {
        int row = wm * 64 + mi * 16 + (lane & 15);
        int slot = (kkk * 4 + lhi) ^ (row & 7);
        af[mi] = *(const bf16x8*)(&Asw[row * BK + slot * 8]);
      }
#pragma unroll
      for (int ni = 0; ni < 2; ++ni) {
        const int col = cb0 + ni * 16 + dx;
        const int cslot = c0s + kkk * 4 + lhi;
        const int idx = ((rw + col) * 16 + (cslot ^ (col & 7))) * 8;
        bfr[ni] = *(const bf16x8*)(&Xs[idx]);
      }
#pragma unroll
      for (int mi = 0; mi < 4; ++mi)
#pragma unroll
        for (int ni = 0; ni < 2; ++ni)
          acc[mi][ni] = __builtin_amdgcn_mfma_f32_16x16x32_bf16(
              af[mi], bfr[ni], acc[mi][ni], 0, 0, 0);
    }
    __builtin_amdgcn_s_setprio(0);

    // single-buffer A: reads done -> overwrite -> visible
    if (step + 1 < NSTEP) {
      __syncthreads();               // all waves finished reading Asw(step)
      STOREA();                      // write Asw(step+1)
      __syncthreads();               // writes visible for next MFMA phase
    }
  }

  // ---- epilogue (proven): C/D col=lane&15, row=(lane>>4)*4+j ----
  const int row0 = (lane >> 4) * 4;
  const int coln = lane & 15;
#pragma unroll
  for (int mi = 0; mi < 4; ++mi) {
    int oc = wm * 64 + mi * 16 + row0;
#pragma unroll
    for (int jj = 0; jj < 4; ++jj) {
      float bv = bias[i * OC + oc + jj];
      float* orow = out + ((size_t)i * OC + oc + jj) * NP;
#pragma unroll
      for (int ni = 0; ni < 2; ++ni) {
        int pg = p0 + wn * 32 + ni * 16 + coln;
        orow[pg] = acc[mi][ni][jj] + bv;
      }
    }
  }
#undef LOADA
#undef STOREA
}

extern "C" void kernel_launch(void* const* d_in, const int* in_sizes, int n_in,
                              void* d_out, int out_size, void* d_ws, size_t ws_size,
                              hipStream_t stream) {
  const float* x    = (const float*)d_in[0];
  const float* w    = (const float*)d_in[1];
  const float* bias = (const float*)d_in[2];
  float* out = (float*)d_out;
  u16* wbf = (u16*)d_ws;   // 32*128*1152 u16 = 9.44 MB

  wcvt_kernel<<<dim3(32 * OC), dim3(128), 0, stream>>>(w, wbf);
  conv_mfma<<<dim3(512), dim3(256), 0, stream>>>(x, wbf, bias, out);
}